// Round 1
// baseline (14671.552 us; speedup 1.0000x reference)
//
#include <hip/hip_runtime.h>
#include <hip/hip_bf16.h>
#include <math.h>

#define V_ 32000
#define D_ 1024
#define H_ 16
#define K_ 64
#define F_ 4096
#define L_ 4
#define S_ 2048
#define B_ 2
#define HK 1024

// ---------------- embedding: x[b,s,:] = emb[tok[b,s],:] + pos[s,:] ----------------
__global__ __launch_bounds__(256) void embed_kernel(
    const int* __restrict__ tok, const float* __restrict__ emb,
    const float* __restrict__ pos, float* __restrict__ x)
{
  int idx = blockIdx.x * 256 + threadIdx.x;      // over B*S*(D/4)
  int d4 = idx & (D_/4 - 1);
  int bs = idx >> 8;                              // D/4 == 256
  int s  = bs & (S_ - 1);
  int t  = tok[bs];
  const float4* e4 = (const float4*)emb;
  const float4* p4 = (const float4*)pos;
  float4 a = e4[(size_t)t * (D_/4) + d4];
  float4 b = p4[(size_t)s * (D_/4) + d4];
  ((float4*)x)[idx] = make_float4(a.x+b.x, a.y+b.y, a.z+b.z, a.w+b.w);
}

// ---------------- fp32 tiled GEMM: C = [res +] A@W + bias, optional ReLU ----------
// A: [M,Kd] row-major, W: [Kd,N] row-major, C: [M,N]. M,N multiples of 64, Kd of 16.
template<bool RELU, bool RES>
__global__ __launch_bounds__(256) void gemm_kernel(
    const float* __restrict__ A, const float* __restrict__ W,
    const float* __restrict__ bias, const float* __restrict__ res,
    float* __restrict__ C, int M, int N, int Kd)
{
  __shared__ float As[16][72];   // [k][m], pad to 72 floats (288B, 16B-aligned rows)
  __shared__ float Bs[16][64];   // [k][n]
  const int t  = threadIdx.x;
  const int tx = t & 15, ty = t >> 4;
  const long bm = (long)blockIdx.x * 64;
  const long bn = (long)blockIdx.y * 64;
  const int ar = t >> 4, ac = t & 15;   // A tile: 64 rows x 16 cols
  const int br = t >> 6, bc = t & 63;   // W tile: 16 rows x 64 cols

  float acc[4][4] = {};

  for (int k0 = 0; k0 < Kd; k0 += 16) {
#pragma unroll
    for (int i = 0; i < 4; ++i)
      As[ac][ar + i*16] = A[(bm + ar + i*16) * (long)Kd + k0 + ac];
#pragma unroll
    for (int i = 0; i < 4; ++i)
      Bs[br + i*4][bc] = W[(long)(k0 + br + i*4) * N + bn + bc];
    __syncthreads();
#pragma unroll
    for (int kk = 0; kk < 16; ++kk) {
      float4 a = *(const float4*)&As[kk][ty*4];
      float4 b = *(const float4*)&Bs[kk][tx*4];
      acc[0][0] += a.x*b.x; acc[0][1] += a.x*b.y; acc[0][2] += a.x*b.z; acc[0][3] += a.x*b.w;
      acc[1][0] += a.y*b.x; acc[1][1] += a.y*b.y; acc[1][2] += a.y*b.z; acc[1][3] += a.y*b.w;
      acc[2][0] += a.z*b.x; acc[2][1] += a.z*b.y; acc[2][2] += a.z*b.z; acc[2][3] += a.z*b.w;
      acc[3][0] += a.w*b.x; acc[3][1] += a.w*b.y; acc[3][2] += a.w*b.z; acc[3][3] += a.w*b.w;
    }
    __syncthreads();
  }

#pragma unroll
  for (int i = 0; i < 4; ++i) {
    long row = bm + ty*4 + i;
#pragma unroll
    for (int j = 0; j < 4; ++j) {
      long col = bn + tx*4 + j;
      float v = acc[i][j] + bias[col];
      if (RES)  v += res[row * (long)N + col];
      if (RELU) v = fmaxf(v, 0.f);
      C[row * (long)N + col] = v;
    }
  }
}

// ---------------- causal flash attention, fp32 ------------------------------------
// Q,K,V,O all [B,S,H*K]. One wave per query row; 4 rows per block share K/V tiles.
__global__ __launch_bounds__(256) void attn_kernel(
    const float* __restrict__ Q, const float* __restrict__ Kb,
    const float* __restrict__ Vb, float* __restrict__ O)
{
  __shared__ float Ks[64][72];
  __shared__ float Vs[64][72];
  __shared__ float Qs[4][64];
  __shared__ float Ps[4][64];
  const int t = threadIdx.x;
  const int wave = t >> 6, lane = t & 63;
  const int bh = blockIdx.y;
  const int b = bh >> 4, h = bh & 15;          // H = 16
  const int q0 = blockIdx.x * 4;
  const int qrow = q0 + wave;
  const size_t rowbase = ((size_t)b * S_ + qrow) * HK + h * 64;

  Qs[wave][lane] = Q[rowbase + lane] * 0.125f; // 1/sqrt(64)
  __syncthreads();
  float4 qreg[16];
#pragma unroll
  for (int d = 0; d < 16; ++d) qreg[d] = *(const float4*)&Qs[wave][d*4];

  float m = -INFINITY, lsum = 0.f, outacc = 0.f;
  const int smax = q0 + 3;
  for (int s0 = 0; s0 <= smax; s0 += 64) {
    // cooperative load of 64x64 K and V tiles (float4, coalesced)
#pragma unroll
    for (int i = 0; i < 4; ++i) {
      int idx = i*256 + t;          // 0..1023 float4 slots
      int r = idx >> 4, c4 = idx & 15;
      size_t g = ((size_t)b * S_ + s0 + r) * HK + h*64 + c4*4;
      *(float4*)&Ks[r][c4*4] = *(const float4*)&Kb[g];
      *(float4*)&Vs[r][c4*4] = *(const float4*)&Vb[g];
    }
    __syncthreads();

    // score for key s0+lane
    float sc = 0.f;
#pragma unroll
    for (int d = 0; d < 16; ++d) {
      float4 kv = *(const float4*)&Ks[lane][d*4];
      sc += qreg[d].x*kv.x + qreg[d].y*kv.y + qreg[d].z*kv.z + qreg[d].w*kv.w;
    }
    int key = s0 + lane;
    if (key > qrow) sc = -INFINITY;

    float tmax = sc;
#pragma unroll
    for (int off = 32; off; off >>= 1) tmax = fmaxf(tmax, __shfl_xor(tmax, off, 64));
    float newm = fmaxf(m, tmax);
    float p = __expf(sc - newm);        // masked lanes: exp(-inf) = 0
    float corr = __expf(m - newm);      // first tile: exp(-inf) = 0
    float psum = p;
#pragma unroll
    for (int off = 32; off; off >>= 1) psum += __shfl_xor(psum, off, 64);
    lsum = lsum * corr + psum;
    m = newm;

    Ps[wave][lane] = p;                 // same-wave LDS write->read, in order
    outacc *= corr;
#pragma unroll
    for (int j = 0; j < 64; ++j) outacc += Ps[wave][j] * Vs[j][lane];
    __syncthreads();                    // protect Ks/Vs before next tile load
  }
  O[rowbase + lane] = outacc / lsum;
}

// ---------------- driver ----------------------------------------------------------
extern "C" void kernel_launch(void* const* d_in, const int* in_sizes, int n_in,
                              void* d_out, int out_size, void* d_ws, size_t ws_size,
                              hipStream_t stream) {
  const int*   tokens = (const int*)  d_in[0];
  const float* emb    = (const float*)d_in[1];
  const float* pos    = (const float*)d_in[2];
  const float* Wq     = (const float*)d_in[3];
  const float* bq     = (const float*)d_in[4];
  const float* Wk     = (const float*)d_in[5];
  const float* bk     = (const float*)d_in[6];
  const float* Wv     = (const float*)d_in[7];
  const float* bv     = (const float*)d_in[8];
  const float* Wo     = (const float*)d_in[9];
  const float* bo     = (const float*)d_in[10];
  const float* W1     = (const float*)d_in[11];
  const float* b1     = (const float*)d_in[12];
  const float* W2     = (const float*)d_in[13];
  const float* b2     = (const float*)d_in[14];
  const float* Wf     = (const float*)d_in[15];
  const float* bf     = (const float*)d_in[16];
  float* out = (float*)d_out;

  const size_t NT = (size_t)B_ * S_;    // 4096 rows
  float* ws  = (float*)d_ws;
  float* x   = ws;                      // NT*D       (4M floats)
  float* q   = x + NT*D_;               // NT*HK
  float* k   = q + NT*HK;               // NT*HK
  float* v   = k + NT*HK;               // NT*HK
  float* att = v + NT*HK;               // NT*HK
  float* hbuf = q;                      // NT*F reuses q..att region (16M floats)

  dim3 blk(256);
  embed_kernel<<<dim3(NT*D_/4/256), blk, 0, stream>>>(tokens, emb, pos, x);

  const int M = (int)NT;
  for (int l = 0; l < L_; ++l) {
    const float* wq = Wq + (size_t)l*D_*HK;  const float* bqL = bq + (size_t)l*HK;
    const float* wk = Wk + (size_t)l*D_*HK;  const float* bkL = bk + (size_t)l*HK;
    const float* wv = Wv + (size_t)l*D_*HK;  const float* bvL = bv + (size_t)l*HK;
    const float* wo = Wo + (size_t)l*HK*D_;  const float* boL = bo + (size_t)l*D_;
    const float* w1 = W1 + (size_t)l*D_*F_;  const float* b1L = b1 + (size_t)l*F_;
    const float* w2 = W2 + (size_t)l*F_*D_;  const float* b2L = b2 + (size_t)l*D_;

    gemm_kernel<false,false><<<dim3(M/64, HK/64), blk, 0, stream>>>(x, wq, bqL, nullptr, q, M, HK, D_);
    gemm_kernel<false,false><<<dim3(M/64, HK/64), blk, 0, stream>>>(x, wk, bkL, nullptr, k, M, HK, D_);
    gemm_kernel<false,false><<<dim3(M/64, HK/64), blk, 0, stream>>>(x, wv, bvL, nullptr, v, M, HK, D_);

    attn_kernel<<<dim3(S_/4, B_*H_), blk, 0, stream>>>(q, k, v, att);

    gemm_kernel<false,true ><<<dim3(M/64, D_/64), blk, 0, stream>>>(att, wo, boL, x, x, M, D_, HK);
    gemm_kernel<true ,false><<<dim3(M/64, F_/64), blk, 0, stream>>>(x, w1, b1L, nullptr, hbuf, M, F_, D_);
    gemm_kernel<false,true ><<<dim3(M/64, D_/64), blk, 0, stream>>>(hbuf, w2, b2L, x, x, M, D_, F_);
  }

  gemm_kernel<false,false><<<dim3(M/64, V_/64), blk, 0, stream>>>(x, Wf, bf, nullptr, out, M, V_, D_);
}